// Round 5
// baseline (473.663 us; speedup 1.0000x reference)
//
#include <hip/hip_runtime.h>

#define N_NODES 100000
#define N_EDGES 800000
#define NEG 0.2f
#define PB_SHIFT 8
#define PB_NODES 256
#define N_PBKT ((N_NODES + PB_NODES - 1) / PB_NODES)   // 391
#define NDEG (N_PBKT * 256)                            // 100096 (padded)
#define PREP_BLOCKS ((N_NODES * 128 / 4 + 255) / 256)  // 12500
#define HIST_BLOCKS 192
#define SCAT_TILE 1024

typedef __attribute__((ext_vector_type(8))) short bf16x8;
typedef __attribute__((ext_vector_type(4))) float f32x4;

__device__ inline unsigned short f2bf(float f) {   // RNE f32 -> bf16
    unsigned u = __float_as_uint(f);
    u += 0x7fffu + ((u >> 16) & 1u);
    return (unsigned short)(u >> 16);
}
__device__ inline float bf2f_lo(unsigned u) { return __uint_as_float(u << 16); }
__device__ inline float bf2f_hi(unsigned u) { return __uint_as_float(u & 0xffff0000u); }

// ---------------------------------------------------------------------------
// prep_w: pack W (and Aalpha = W·a, ct==8) into MFMA B-fragment order.
// Also zeroes the per-node degree arrays (incl. pad tail) and adj end-pads.
// ---------------------------------------------------------------------------
__global__ __launch_bounds__(256) void prep_w_kernel(
    const float* __restrict__ W_in, const float* __restrict__ W_out,
    const float* __restrict__ as_in, const float* __restrict__ ad_in,
    const float* __restrict__ as_out, const float* __restrict__ ad_out,
    unsigned short* __restrict__ Wf,
    int* __restrict__ deg0, int* __restrict__ deg1,
    int* __restrict__ adj_in, int* __restrict__ adj_out)
{
    const int t = blockIdx.x * 256 + threadIdx.x;
    if (t < NDEG) { deg0[t] = 0; deg1[t] = 0; }
    if (t < 8) { adj_in[N_EDGES + t] = 0; adj_out[N_EDGES + t] = 0; }
    if (t >= 2 * 4 * 9 * 64) return;
    const int lane = t & 63;
    const int rest = t >> 6;
    const int ct  = rest % 9;
    const int kb  = (rest / 9) & 3;
    const int dir = rest / 36;
    const float* W  = dir ? W_out  : W_in;
    const float* as = dir ? as_out : as_in;
    const float* ad = dir ? ad_out : ad_in;
    const int m16 = lane & 15, quad = lane >> 4;

    bf16x8 o;
#pragma unroll
    for (int j = 0; j < 8; ++j) {
        const int k = kb * 32 + quad * 8 + j;
        float v;
        if (ct < 8) {
            v = W[k * 128 + ct * 16 + m16];
        } else {
            const float* av = (m16 < 8) ? as : ad;
            const int hh = m16 & 7;
            v = 0.f;
            for (int c = 0; c < 16; ++c)
                v += W[k * 128 + hh * 16 + c] * av[hh * 16 + c];
        }
        o[j] = (short)f2bf(v);
    }
    *(bf16x8*)&Wf[(long long)t * 8] = o;
}

// ---------------------------------------------------------------------------
// fused prep_x + per-node degree count (direct global atomics, L2-resident).
// ---------------------------------------------------------------------------
__global__ __launch_bounds__(256) void prep_hist_kernel(
    const float* __restrict__ x, unsigned short* __restrict__ x_bf,
    const int* __restrict__ ei,
    int* __restrict__ deg0, int* __restrict__ deg1)
{
    const int tid = threadIdx.x;
    if (blockIdx.x < PREP_BLOCKS) {
        const int i = (blockIdx.x * 256 + tid) * 4;
        if (i >= N_NODES * 128) return;
        const float4 v = *(const float4*)&x[i];
        ushort4 o;
        o.x = f2bf(v.x); o.y = f2bf(v.y); o.z = f2bf(v.z); o.w = f2bf(v.w);
        *(ushort4*)&x_bf[i] = o;
        return;
    }
    const int hb = blockIdx.x - PREP_BLOCKS;
    for (int e = hb * 256 + tid; e < N_EDGES; e += HIST_BLOCKS * 256) {
        const int s = ei[e];
        const int t = ei[N_EDGES + e];
        atomicAdd(&deg0[t], 1);    // dir0: group by dst
        atomicAdd(&deg1[s], 1);    // dir1: group by src
    }
}

// ---------------------------------------------------------------------------
// gemm: h = bf16(x) @ bf16(W) via MFMA; alpha logits from the 9th column tile.
// ---------------------------------------------------------------------------
__global__ __launch_bounds__(256) void gemm_kernel(
    const unsigned short* __restrict__ x_bf,
    const unsigned short* __restrict__ Wf,
    unsigned short* __restrict__ h_in, unsigned short* __restrict__ h_out,
    float* __restrict__ asrc_in, float* __restrict__ adst_in,
    float* __restrict__ asrc_out, float* __restrict__ adst_out)
{
    const int dir = blockIdx.y;
    unsigned short* h = dir ? h_out : h_in;
    float* asrc = dir ? asrc_out : asrc_in;
    float* adst = dir ? adst_out : adst_in;

    const int tid  = threadIdx.x;
    const int lane = tid & 63;
    const int wave = tid >> 6;
    const int m16  = lane & 15;
    const int quad = lane >> 4;
    const int rbase = blockIdx.x * 128 + wave * 32;

    f32x4 acc[2][8];
    f32x4 acc_a[2];
#pragma unroll
    for (int rt = 0; rt < 2; ++rt) {
        acc_a[rt] = f32x4{0.f, 0.f, 0.f, 0.f};
#pragma unroll
        for (int ct = 0; ct < 8; ++ct)
            acc[rt][ct] = f32x4{0.f, 0.f, 0.f, 0.f};
    }

    const unsigned short* wf = Wf + (long long)dir * 4 * 9 * 64 * 8;

#pragma unroll
    for (int kb = 0; kb < 4; ++kb) {
        const int k0 = kb * 32 + quad * 8;
        bf16x8 a[2];
#pragma unroll
        for (int rt = 0; rt < 2; ++rt) {
            int r = rbase + rt * 16 + m16;
            r = r < N_NODES ? r : N_NODES - 1;   // clamp: stores are guarded
            a[rt] = *(const bf16x8*)&x_bf[(long long)r * 128 + k0];
        }
#pragma unroll
        for (int ct = 0; ct < 9; ++ct) {
            const bf16x8 b = *(const bf16x8*)&wf[(long long)((kb * 9 + ct) * 64 + lane) * 8];
            if (ct < 8) {
                acc[0][ct] = __builtin_amdgcn_mfma_f32_16x16x32_bf16(a[0], b, acc[0][ct], 0, 0, 0);
                acc[1][ct] = __builtin_amdgcn_mfma_f32_16x16x32_bf16(a[1], b, acc[1][ct], 0, 0, 0);
            } else {
                acc_a[0] = __builtin_amdgcn_mfma_f32_16x16x32_bf16(a[0], b, acc_a[0], 0, 0, 0);
                acc_a[1] = __builtin_amdgcn_mfma_f32_16x16x32_bf16(a[1], b, acc_a[1], 0, 0, 0);
            }
        }
    }

#pragma unroll
    for (int rt = 0; rt < 2; ++rt) {
#pragma unroll
        for (int r = 0; r < 4; ++r) {
            const int row = rbase + rt * 16 + quad * 4 + r;
            if (row < N_NODES) {
                unsigned short* hp = &h[(long long)row * 128 + m16];
#pragma unroll
                for (int ct = 0; ct < 8; ++ct)
                    hp[ct * 16] = f2bf(acc[rt][ct][r]);
                const float av = acc_a[rt][r];
                if (m16 < 8) asrc[row * 8 + m16] = av;
                else         adst[row * 8 + (m16 - 8)] = av;
            }
        }
    }
}

// ---------------------------------------------------------------------------
// bsum: per-bucket degree sums (input to the 391-entry scan).
// ---------------------------------------------------------------------------
__global__ __launch_bounds__(256) void bsum_kernel(
    const int* __restrict__ deg0, const int* __restrict__ deg1,
    int* __restrict__ bsum)
{
    const int dir = blockIdx.y;
    const int* deg = dir ? deg1 : deg0;
    __shared__ int sm[256];
    const int tid = threadIdx.x;
    sm[tid] = deg[blockIdx.x * 256 + tid];
    __syncthreads();
#pragma unroll
    for (int off = 1; off < 256; off <<= 1) {
        int t = (tid >= off) ? sm[tid - off] : 0;
        __syncthreads();
        sm[tid] += t;
        __syncthreads();
    }
    if (tid == 255) bsum[dir * N_PBKT + blockIdx.x] = sm[255];
}

// ---------------------------------------------------------------------------
// bucket scan: exclusive scan of the 391 bucket sums per dir -> boffs.
// ---------------------------------------------------------------------------
__global__ __launch_bounds__(512) void bucket_scan_kernel(
    const int* __restrict__ bsum,
    int* __restrict__ boffs0, int* __restrict__ boffs1,
    int* __restrict__ offs_in, int* __restrict__ offs_out)
{
    const int dir = blockIdx.x;
    const int* c = bsum + dir * N_PBKT;
    int* bo = dir ? boffs1 : boffs0;

    __shared__ int sm[512];
    const int tid = threadIdx.x;
    const int v = (tid < N_PBKT) ? c[tid] : 0;
    sm[tid] = v;
    __syncthreads();
#pragma unroll
    for (int off = 1; off < 512; off <<= 1) {
        int t = (tid >= off) ? sm[tid - off] : 0;
        __syncthreads();
        sm[tid] += t;
        __syncthreads();
    }
    if (tid < N_PBKT) bo[tid] = sm[tid] - v;
    if (tid == 0) (dir ? offs_out : offs_in)[N_NODES] = N_EDGES;
}

// ---------------------------------------------------------------------------
// fixup: fine exclusive scan within each bucket + bucket base -> offs, cur.
// ---------------------------------------------------------------------------
__global__ __launch_bounds__(256) void fixup_kernel(
    const int* __restrict__ deg0, const int* __restrict__ deg1,
    const int* __restrict__ boffs0, const int* __restrict__ boffs1,
    int* __restrict__ offs_in, int* __restrict__ offs_out,
    int* __restrict__ cur0, int* __restrict__ cur1)
{
    const int dir = blockIdx.y;
    const int* deg = dir ? deg1 : deg0;
    const int* bo  = dir ? boffs1 : boffs0;
    int* offs = dir ? offs_out : offs_in;
    int* cur  = dir ? cur1 : cur0;

    __shared__ int sm[256];
    const int tid = threadIdx.x;
    const int node = blockIdx.x * 256 + tid;
    const int v = deg[node];
    sm[tid] = v;
    __syncthreads();
#pragma unroll
    for (int off = 1; off < 256; off <<= 1) {
        int t = (tid >= off) ? sm[tid - off] : 0;
        __syncthreads();
        sm[tid] += t;
        __syncthreads();
    }
    const int excl = bo[blockIdx.x] + sm[tid] - v;
    if (node < N_NODES) { offs[node] = excl; cur[node] = excl; }
}

// ---------------------------------------------------------------------------
// scatter: direct counting-sort placement. One read of ei; two global-atomic
// cursor bumps + two adj writes per edge. Replaces partition+place (which
// moved every edge 3x through memory via the binned intermediate).
// ---------------------------------------------------------------------------
__global__ __launch_bounds__(256) void scatter_kernel(
    const int* __restrict__ ei,
    int* __restrict__ cur0, int* __restrict__ cur1,
    int* __restrict__ adj_in, int* __restrict__ adj_out)
{
    const int tid = threadIdx.x;
    const int e0 = blockIdx.x * SCAT_TILE;
#pragma unroll
    for (int i = 0; i < SCAT_TILE / 256; ++i) {
        const int e = e0 + i * 256 + tid;
        if (e < N_EDGES) {
            const int s = ei[e];
            const int t = ei[N_EDGES + e];
            adj_in[atomicAdd(&cur0[t], 1)] = s;
            adj_out[atomicAdd(&cur1[s], 1)] = t;
        }
    }
}

// ---------------------------------------------------------------------------
// Gather v5 (round-3 form, unchanged): one wave per node, wave-uniform n so
// offs/adj go through the scalar pipe; single padded branch-free 8-stride
// loop; inline asrc+leaky+exp (1 exp per 8 visits); den via 3x shfl_xor.
// ---------------------------------------------------------------------------
__global__ __launch_bounds__(256) void gather_kernel(
    const int* __restrict__ offs_in, const int* __restrict__ adj_in,
    const int* __restrict__ offs_out, const int* __restrict__ adj_out,
    const unsigned short* __restrict__ h_in, const unsigned short* __restrict__ h_out,
    const float* __restrict__ asrc_in, const float* __restrict__ adst_in,
    const float* __restrict__ asrc_out, const float* __restrict__ adst_out,
    const float* __restrict__ b_in, const float* __restrict__ b_out,
    float* __restrict__ out)
{
    int n = (blockIdx.x * 256 + threadIdx.x) >> 6;
    if (n >= N_NODES) return;
    n = __builtin_amdgcn_readfirstlane(n);
    const int lane = threadIdx.x & 63;
    const int c0 = lane * 2;
    const int hh = lane >> 3;        // head this lane accumulates for
    const int g8 = lane & 7;         // neighbor slot this lane owns
    const int grpbase = lane & 56;   // hh*8: base lane of this head group

    float acc0 = b_in[c0] + b_out[c0];
    float acc1 = b_in[c0 + 1] + b_out[c0 + 1];

#define DIR_BLOCK(OFFS, ADJ, HX, ASRC, ADST)                                   \
    {                                                                          \
        const int beg = OFFS[n], end = OFFS[n + 1];                            \
        if (end > beg) {                                                       \
            const float ad = ADST[n * 8 + hh];                                 \
            float num0 = 0.f, num1 = 0.f, den = 0.f;                           \
            for (int p = beg; p < end; p += 8) {                               \
                const int q = p + g8;                                          \
                const int nbv = ADJ[q];               /* vector ld, padded */  \
                float l = ASRC[nbv * 8 + hh] + ad;                             \
                l = l > 0.f ? l : NEG * l;                                     \
                float w = __expf(l);                                           \
                w = (q < end) ? w : 0.f;                                       \
                den += w;                                                      \
                _Pragma("unroll")                                              \
                for (int g = 0; g < 8; ++g) {                                  \
                    const int nb = ADJ[p + g];        /* scalar (uniform) */   \
                    const float w_g = __shfl(w, grpbase + g, 64);              \
                    const unsigned hv = *(const unsigned*)&HX[(long long)nb * 128 + c0]; \
                    num0 += w_g * bf2f_lo(hv);                                 \
                    num1 += w_g * bf2f_hi(hv);                                 \
                }                                                              \
            }                                                                  \
            den += __shfl_xor(den, 1, 64);                                     \
            den += __shfl_xor(den, 2, 64);                                     \
            den += __shfl_xor(den, 4, 64);                                     \
            const float rden = 1.f / den;                                      \
            acc0 += num0 * rden;                                               \
            acc1 += num1 * rden;                                               \
        }                                                                      \
    }

    DIR_BLOCK(offs_in, adj_in, h_in, asrc_in, adst_in)
    DIR_BLOCK(offs_out, adj_out, h_out, asrc_out, adst_out)
#undef DIR_BLOCK

    *(float2*)&out[(long long)n * 128 + c0] = float2{acc0, acc1};
}

extern "C" void kernel_launch(void* const* d_in, const int* in_sizes, int n_in,
                              void* d_out, int out_size, void* d_ws, size_t ws_size,
                              hipStream_t stream) {
    const float* x      = (const float*)d_in[0];
    const int*   ei     = (const int*)  d_in[1];
    const float* W_in   = (const float*)d_in[2];
    const float* as_in  = (const float*)d_in[3];
    const float* ad_in  = (const float*)d_in[4];
    const float* b_in   = (const float*)d_in[5];
    const float* W_out  = (const float*)d_in[6];
    const float* as_out = (const float*)d_in[7];
    const float* ad_out = (const float*)d_in[8];
    const float* b_out  = (const float*)d_in[9];
    float* out = (float*)d_out;

    char* ws = (char*)d_ws;
    const long long NH = (long long)N_NODES * 128;
    unsigned short* x_bf  = (unsigned short*)ws;    ws += NH * 2;
    unsigned short* h_in  = (unsigned short*)ws;    ws += NH * 2;
    unsigned short* h_out = (unsigned short*)ws;    ws += NH * 2;
    unsigned short* Wf    = (unsigned short*)ws;    ws += 2LL * 4 * 9 * 64 * 8 * 2;
    float* asrc_in   = (float*)ws;                  ws += N_NODES * 8 * 4;
    float* adst_in   = (float*)ws;                  ws += N_NODES * 8 * 4;
    float* asrc_out  = (float*)ws;                  ws += N_NODES * 8 * 4;
    float* adst_out  = (float*)ws;                  ws += N_NODES * 8 * 4;
    int* adj_in      = (int*)ws;                    ws += (N_EDGES + 8) * 4;
    int* adj_out     = (int*)ws;                    ws += (N_EDGES + 8) * 4;
    int* offs_in     = (int*)ws;                    ws += (N_NODES + 1) * 4;
    int* offs_out    = (int*)ws;                    ws += (N_NODES + 1) * 4;
    int* deg0        = (int*)ws;                    ws += NDEG * 4;
    int* deg1        = (int*)ws;                    ws += NDEG * 4;
    int* cur0        = (int*)ws;                    ws += NDEG * 4;
    int* cur1        = (int*)ws;                    ws += NDEG * 4;
    int* bsum        = (int*)ws;                    ws += 2 * N_PBKT * 4;
    int* boffs0      = (int*)ws;                    ws += (N_PBKT + 1) * 4;
    int* boffs1      = (int*)ws;                    ws += (N_PBKT + 1) * 4;

    prep_w_kernel<<<(NDEG + 255) / 256, 256, 0, stream>>>(
        W_in, W_out, as_in, ad_in, as_out, ad_out, Wf, deg0, deg1, adj_in, adj_out);
    prep_hist_kernel<<<PREP_BLOCKS + HIST_BLOCKS, 256, 0, stream>>>(
        x, x_bf, ei, deg0, deg1);

    dim3 gemm_grid((N_NODES + 127) / 128, 2);
    gemm_kernel<<<gemm_grid, 256, 0, stream>>>(
        x_bf, Wf, h_in, h_out, asrc_in, adst_in, asrc_out, adst_out);

    bsum_kernel<<<dim3(N_PBKT, 2), 256, 0, stream>>>(deg0, deg1, bsum);
    bucket_scan_kernel<<<2, 512, 0, stream>>>(
        bsum, boffs0, boffs1, offs_in, offs_out);
    fixup_kernel<<<dim3(N_PBKT, 2), 256, 0, stream>>>(
        deg0, deg1, boffs0, boffs1, offs_in, offs_out, cur0, cur1);
    scatter_kernel<<<(N_EDGES + SCAT_TILE - 1) / SCAT_TILE, 256, 0, stream>>>(
        ei, cur0, cur1, adj_in, adj_out);

    gather_kernel<<<(N_NODES * 64 + 255) / 256, 256, 0, stream>>>(
        offs_in, adj_in, offs_out, adj_out, h_in, h_out,
        asrc_in, adst_in, asrc_out, adst_out, b_in, b_out, out);
}

// Round 6
// 280.790 us; speedup vs baseline: 1.6869x; 1.6869x over previous
//
#include <hip/hip_runtime.h>

#define N_NODES 100000
#define N_EDGES 800000
#define NEG 0.2f
#define PB_SHIFT 8
#define PB_NODES 256
#define N_PBKT ((N_NODES + PB_NODES - 1) / PB_NODES)   // 391
#define TILE_E 4096
#define EPT 16          // edges per thread in partition (TILE_E / 256)
#define HIST_BLOCKS 192

typedef __attribute__((ext_vector_type(8))) short bf16x8;
typedef __attribute__((ext_vector_type(4))) float f32x4;

__device__ inline unsigned short f2bf(float f) {   // RNE f32 -> bf16
    unsigned u = __float_as_uint(f);
    u += 0x7fffu + ((u >> 16) & 1u);
    return (unsigned short)(u >> 16);
}
__device__ inline float bf2f_lo(unsigned u) { return __uint_as_float(u << 16); }
__device__ inline float bf2f_hi(unsigned u) { return __uint_as_float(u & 0xffff0000u); }

// ---------------------------------------------------------------------------
// prep_w: pack W (and Aalpha = W·a, ct==8) into MFMA B-fragment order.
// Also zeroes the bucket-count array and the adj end-pads. Runs BEFORE the
// hist kernel (bcnt must be zeroed in a prior dispatch).
// ---------------------------------------------------------------------------
__global__ __launch_bounds__(256) void prep_w_kernel(
    const float* __restrict__ W_in, const float* __restrict__ W_out,
    const float* __restrict__ as_in, const float* __restrict__ ad_in,
    const float* __restrict__ as_out, const float* __restrict__ ad_out,
    unsigned short* __restrict__ Wf, int* __restrict__ bcnt,
    int* __restrict__ adj_in, int* __restrict__ adj_out)
{
    const int t = blockIdx.x * 256 + threadIdx.x;
    if (t < 2 * N_PBKT) bcnt[t] = 0;
    if (t < 8) { adj_in[N_EDGES + t] = 0; adj_out[N_EDGES + t] = 0; }
    if (t >= 2 * 4 * 9 * 64) return;
    const int lane = t & 63;
    const int rest = t >> 6;
    const int ct  = rest % 9;
    const int kb  = (rest / 9) & 3;
    const int dir = rest / 36;
    const float* W  = dir ? W_out  : W_in;
    const float* as = dir ? as_out : as_in;
    const float* ad = dir ? ad_out : ad_in;
    const int m16 = lane & 15, quad = lane >> 4;

    bf16x8 o;
#pragma unroll
    for (int j = 0; j < 8; ++j) {
        const int k = kb * 32 + quad * 8 + j;
        float v;
        if (ct < 8) {
            v = W[k * 128 + ct * 16 + m16];
        } else {
            const float* av = (m16 < 8) ? as : ad;
            const int hh = m16 & 7;
            v = 0.f;
            for (int c = 0; c < 16; ++c)
                v += W[k * 128 + hh * 16 + c] * av[hh * 16 + c];
        }
        o[j] = (short)f2bf(v);
    }
    *(bf16x8*)&Wf[(long long)t * 8] = o;
}

// ---------------------------------------------------------------------------
// hist: coarse bucket histogram (LDS-staged; few global atomics).
// ---------------------------------------------------------------------------
__global__ __launch_bounds__(256) void hist_kernel(
    const int* __restrict__ ei, int* __restrict__ bcnt)
{
    const int tid = threadIdx.x;
    __shared__ int bh[2 * N_PBKT];
    for (int i = tid; i < 2 * N_PBKT; i += 256) bh[i] = 0;
    __syncthreads();
    for (int e = blockIdx.x * 256 + tid; e < N_EDGES; e += HIST_BLOCKS * 256) {
        const int s = ei[e];
        const int t = ei[N_EDGES + e];
        atomicAdd(&bh[t >> PB_SHIFT], 1);               // dir0: group by dst
        atomicAdd(&bh[N_PBKT + (s >> PB_SHIFT)], 1);    // dir1: group by src
    }
    __syncthreads();
    for (int i = tid; i < 2 * N_PBKT; i += 256) {
        const int v = bh[i];
        if (v) atomicAdd(&bcnt[i], v);
    }
}

// ---------------------------------------------------------------------------
// gemm: h = bf16(x) @ bf16(W) via MFMA; alpha logits from the 9th column
// tile. Reads x as f32 DIRECTLY and converts in-register (identical RNE to
// the old x_bf path) — eliminates the x_bf round-trip and its dispatch.
// ---------------------------------------------------------------------------
__global__ __launch_bounds__(256) void gemm_kernel(
    const float* __restrict__ x,
    const unsigned short* __restrict__ Wf,
    unsigned short* __restrict__ h_in, unsigned short* __restrict__ h_out,
    float* __restrict__ asrc_in, float* __restrict__ adst_in,
    float* __restrict__ asrc_out, float* __restrict__ adst_out)
{
    const int dir = blockIdx.y;
    unsigned short* h = dir ? h_out : h_in;
    float* asrc = dir ? asrc_out : asrc_in;
    float* adst = dir ? adst_out : adst_in;

    const int tid  = threadIdx.x;
    const int lane = tid & 63;
    const int wave = tid >> 6;
    const int m16  = lane & 15;
    const int quad = lane >> 4;
    const int rbase = blockIdx.x * 128 + wave * 32;

    f32x4 acc[2][8];
    f32x4 acc_a[2];
#pragma unroll
    for (int rt = 0; rt < 2; ++rt) {
        acc_a[rt] = f32x4{0.f, 0.f, 0.f, 0.f};
#pragma unroll
        for (int ct = 0; ct < 8; ++ct)
            acc[rt][ct] = f32x4{0.f, 0.f, 0.f, 0.f};
    }

    const unsigned short* wf = Wf + (long long)dir * 4 * 9 * 64 * 8;

#pragma unroll
    for (int kb = 0; kb < 4; ++kb) {
        const int k0 = kb * 32 + quad * 8;
        bf16x8 a[2];
#pragma unroll
        for (int rt = 0; rt < 2; ++rt) {
            int r = rbase + rt * 16 + m16;
            r = r < N_NODES ? r : N_NODES - 1;   // clamp: stores are guarded
            const float4 v0 = *(const float4*)&x[(long long)r * 128 + k0];
            const float4 v1 = *(const float4*)&x[(long long)r * 128 + k0 + 4];
            a[rt][0] = (short)f2bf(v0.x); a[rt][1] = (short)f2bf(v0.y);
            a[rt][2] = (short)f2bf(v0.z); a[rt][3] = (short)f2bf(v0.w);
            a[rt][4] = (short)f2bf(v1.x); a[rt][5] = (short)f2bf(v1.y);
            a[rt][6] = (short)f2bf(v1.z); a[rt][7] = (short)f2bf(v1.w);
        }
#pragma unroll
        for (int ct = 0; ct < 9; ++ct) {
            const bf16x8 b = *(const bf16x8*)&wf[(long long)((kb * 9 + ct) * 64 + lane) * 8];
            if (ct < 8) {
                acc[0][ct] = __builtin_amdgcn_mfma_f32_16x16x32_bf16(a[0], b, acc[0][ct], 0, 0, 0);
                acc[1][ct] = __builtin_amdgcn_mfma_f32_16x16x32_bf16(a[1], b, acc[1][ct], 0, 0, 0);
            } else {
                acc_a[0] = __builtin_amdgcn_mfma_f32_16x16x32_bf16(a[0], b, acc_a[0], 0, 0, 0);
                acc_a[1] = __builtin_amdgcn_mfma_f32_16x16x32_bf16(a[1], b, acc_a[1], 0, 0, 0);
            }
        }
    }

#pragma unroll
    for (int rt = 0; rt < 2; ++rt) {
#pragma unroll
        for (int r = 0; r < 4; ++r) {
            const int row = rbase + rt * 16 + quad * 4 + r;
            if (row < N_NODES) {
                unsigned short* hp = &h[(long long)row * 128 + m16];
#pragma unroll
                for (int ct = 0; ct < 8; ++ct)
                    hp[ct * 16] = f2bf(acc[rt][ct][r]);
                const float av = acc_a[rt][r];
                if (m16 < 8) asrc[row * 8 + m16] = av;
                else         adst[row * 8 + (m16 - 8)] = av;
            }
        }
    }
}

// ---------------------------------------------------------------------------
// CSR build: scan bucket counts -> boffs (persistent) + gcur (consumed)
// ---------------------------------------------------------------------------
__global__ __launch_bounds__(512) void bucket_scan_kernel(
    const int* __restrict__ bcnt,
    int* __restrict__ boffs0, int* __restrict__ boffs1,
    int* __restrict__ gcur,
    int* __restrict__ offs_in, int* __restrict__ offs_out)
{
    const int dir = blockIdx.x;
    const int* c = bcnt + dir * N_PBKT;
    int* bo = dir ? boffs1 : boffs0;
    int* gc = gcur + dir * N_PBKT;

    __shared__ int sm[512];
    const int tid = threadIdx.x;
    const int v = (tid < N_PBKT) ? c[tid] : 0;
    sm[tid] = v;
    __syncthreads();
#pragma unroll
    for (int off = 1; off < 512; off <<= 1) {
        int t = (tid >= off) ? sm[tid - off] : 0;
        __syncthreads();
        sm[tid] += t;
        __syncthreads();
    }
    if (tid < N_PBKT) {
        const int excl = sm[tid] - v;
        bo[tid] = excl;
        gc[tid] = excl;
    }
    if (tid == N_PBKT - 1) bo[N_PBKT] = sm[tid];   // == N_EDGES
    if (tid == 0) (dir ? offs_out : offs_in)[N_NODES] = N_EDGES;
}

// partition (merged dirs, TILE 4096): both direction histograms + scatters
// from ONE read of ei. LDS hist -> one global atomic per (block,bucket).
__global__ __launch_bounds__(256) void partition_kernel(
    const int* __restrict__ ei, int* __restrict__ gcur,
    int* __restrict__ binned0, int* __restrict__ binned1)
{
    __shared__ int hist0[N_PBKT];
    __shared__ int curs0[N_PBKT];
    __shared__ int hist1[N_PBKT];
    __shared__ int curs1[N_PBKT];
    const int tid = threadIdx.x;
    for (int i = tid; i < N_PBKT; i += 256) { hist0[i] = 0; hist1[i] = 0; }
    __syncthreads();

    const int e0 = blockIdx.x * TILE_E;
    int sv[EPT], tv[EPT];
#pragma unroll
    for (int i = 0; i < EPT; ++i) {
        const int e = e0 + i * 256 + tid;
        if (e < N_EDGES) {
            sv[i] = ei[e];
            tv[i] = ei[N_EDGES + e];
            atomicAdd(&hist0[tv[i] >> PB_SHIFT], 1);   // dir0: group by dst
            atomicAdd(&hist1[sv[i] >> PB_SHIFT], 1);   // dir1: group by src
        } else {
            sv[i] = -1; tv[i] = 0;
        }
    }
    __syncthreads();
    for (int b = tid; b < N_PBKT; b += 256) {
        int c = hist0[b];
        curs0[b] = c ? atomicAdd(&gcur[b], c) : 0;
        c = hist1[b];
        curs1[b] = c ? atomicAdd(&gcur[N_PBKT + b], c) : 0;
    }
    __syncthreads();
#pragma unroll
    for (int i = 0; i < EPT; ++i) {
        if (sv[i] >= 0) {
            int pos = atomicAdd(&curs0[tv[i] >> PB_SHIFT], 1);
            binned0[pos] = (sv[i] << 8) | (tv[i] & (PB_NODES - 1));
            pos = atomicAdd(&curs1[sv[i] >> PB_SHIFT], 1);
            binned1[pos] = (tv[i] << 8) | (sv[i] & (PB_NODES - 1));
        }
    }
}

// place: one block per bucket; fine count+scan+cursors in LDS; adj writes
// land in a contiguous ~8KB region. Pure scatter.
__global__ __launch_bounds__(256) void place_kernel(
    const int* __restrict__ binned0, const int* __restrict__ binned1,
    const int* __restrict__ boffs0, const int* __restrict__ boffs1,
    int* __restrict__ adj_in, int* __restrict__ adj_out,
    int* __restrict__ offs_in, int* __restrict__ offs_out)
{
    const int b   = blockIdx.x;
    const int dir = blockIdx.y;
    const int* bp = dir ? binned1 : binned0;
    const int* bo = dir ? boffs1  : boffs0;
    int* adj  = dir ? adj_out  : adj_in;
    int* offs = dir ? offs_out : offs_in;

    const int base = b << PB_SHIFT;
    const int beg = bo[b], end = bo[b + 1];
    const int tid = threadIdx.x;

    __shared__ int cnt[PB_NODES];
    __shared__ int sc[PB_NODES];
    __shared__ int cur[PB_NODES];

    cnt[tid] = 0;
    __syncthreads();
    for (int p = beg + tid; p < end; p += 256)
        atomicAdd(&cnt[bp[p] & (PB_NODES - 1)], 1);
    __syncthreads();
    const int v = cnt[tid];
    sc[tid] = v;
    __syncthreads();
#pragma unroll
    for (int off = 1; off < PB_NODES; off <<= 1) {
        int t = (tid >= off) ? sc[tid - off] : 0;
        __syncthreads();
        sc[tid] += t;
        __syncthreads();
    }
    const int excl = beg + sc[tid] - v;
    cur[tid] = excl;
    const int node = base + tid;
    if (node < N_NODES) offs[node] = excl;
    __syncthreads();
    for (int p = beg + tid; p < end; p += 256) {
        const int pk = bp[p];
        adj[atomicAdd(&cur[pk & (PB_NODES - 1)], 1)] = pk >> 8;
    }
}

// ---------------------------------------------------------------------------
// Gather v7: v5 structure (wave per node, uniform n, padded 8-stride loop,
// inline asrc+leaky+exp) but the 8 per-group __shfl broadcasts are replaced
// by 1 ds_write_b32 + 2 ds_read_b128: lane (hh,g8) writes w to sw[hh*8+g8];
// each lane then reads its head-group's 8 weights as two f32x4 (broadcast
// reads, 2-way bank aliasing = free). Wave-synchronous; numerics identical.
// ---------------------------------------------------------------------------
__global__ __launch_bounds__(256) void gather_kernel(
    const int* __restrict__ offs_in, const int* __restrict__ adj_in,
    const int* __restrict__ offs_out, const int* __restrict__ adj_out,
    const unsigned short* __restrict__ h_in, const unsigned short* __restrict__ h_out,
    const float* __restrict__ asrc_in, const float* __restrict__ adst_in,
    const float* __restrict__ asrc_out, const float* __restrict__ adst_out,
    const float* __restrict__ b_in, const float* __restrict__ b_out,
    float* __restrict__ out)
{
    int n = (blockIdx.x * 256 + threadIdx.x) >> 6;
    if (n >= N_NODES) return;
    n = __builtin_amdgcn_readfirstlane(n);
    const int lane = threadIdx.x & 63;
    const int wave = threadIdx.x >> 6;
    const int c0 = lane * 2;
    const int hh = lane >> 3;        // head this lane accumulates for
    const int g8 = lane & 7;         // neighbor slot this lane owns

    __shared__ __align__(16) float swbuf[4][64];
    float* sw = swbuf[wave];

    float acc0 = b_in[c0] + b_out[c0];
    float acc1 = b_in[c0 + 1] + b_out[c0 + 1];

#define DIR_BLOCK(OFFS, ADJ, HX, ASRC, ADST)                                   \
    {                                                                          \
        const int beg = OFFS[n], end = OFFS[n + 1];                            \
        if (end > beg) {                                                       \
            const float ad = ADST[n * 8 + hh];                                 \
            float num0 = 0.f, num1 = 0.f, den = 0.f;                           \
            for (int p = beg; p < end; p += 8) {                               \
                const int q = p + g8;                                          \
                const int nbv = ADJ[q];               /* vector ld, padded */  \
                float l = ASRC[nbv * 8 + hh] + ad;                             \
                l = l > 0.f ? l : NEG * l;                                     \
                float w = __expf(l);                                           \
                w = (q < end) ? w : 0.f;                                       \
                den += w;                                                      \
                sw[hh * 8 + g8] = w;                                           \
                __builtin_amdgcn_wave_barrier();                               \
                const f32x4 w03 = *(const f32x4*)&sw[hh * 8];                  \
                const f32x4 w47 = *(const f32x4*)&sw[hh * 8 + 4];              \
                __builtin_amdgcn_wave_barrier();                               \
                _Pragma("unroll")                                              \
                for (int g = 0; g < 8; ++g) {                                  \
                    const int nb = ADJ[p + g];        /* scalar (uniform) */   \
                    const float w_g = (g < 4) ? w03[g & 3] : w47[g & 3];       \
                    const unsigned hv = *(const unsigned*)&HX[(long long)nb * 128 + c0]; \
                    num0 += w_g * bf2f_lo(hv);                                 \
                    num1 += w_g * bf2f_hi(hv);                                 \
                }                                                              \
            }                                                                  \
            den += __shfl_xor(den, 1, 64);                                     \
            den += __shfl_xor(den, 2, 64);                                     \
            den += __shfl_xor(den, 4, 64);                                     \
            const float rden = 1.f / den;                                      \
            acc0 += num0 * rden;                                               \
            acc1 += num1 * rden;                                               \
        }                                                                      \
    }

    DIR_BLOCK(offs_in, adj_in, h_in, asrc_in, adst_in)
    DIR_BLOCK(offs_out, adj_out, h_out, asrc_out, adst_out)
#undef DIR_BLOCK

    *(float2*)&out[(long long)n * 128 + c0] = float2{acc0, acc1};
}

extern "C" void kernel_launch(void* const* d_in, const int* in_sizes, int n_in,
                              void* d_out, int out_size, void* d_ws, size_t ws_size,
                              hipStream_t stream) {
    const float* x      = (const float*)d_in[0];
    const int*   ei     = (const int*)  d_in[1];
    const float* W_in   = (const float*)d_in[2];
    const float* as_in  = (const float*)d_in[3];
    const float* ad_in  = (const float*)d_in[4];
    const float* b_in   = (const float*)d_in[5];
    const float* W_out  = (const float*)d_in[6];
    const float* as_out = (const float*)d_in[7];
    const float* ad_out = (const float*)d_in[8];
    const float* b_out  = (const float*)d_in[9];
    float* out = (float*)d_out;

    char* ws = (char*)d_ws;
    const long long NH = (long long)N_NODES * 128;
    unsigned short* h_in  = (unsigned short*)ws;    ws += NH * 2;
    unsigned short* h_out = (unsigned short*)ws;    ws += NH * 2;
    unsigned short* Wf    = (unsigned short*)ws;    ws += 2LL * 4 * 9 * 64 * 8 * 2;
    float* asrc_in   = (float*)ws;                  ws += N_NODES * 8 * 4;
    float* adst_in   = (float*)ws;                  ws += N_NODES * 8 * 4;
    float* asrc_out  = (float*)ws;                  ws += N_NODES * 8 * 4;
    float* adst_out  = (float*)ws;                  ws += N_NODES * 8 * 4;
    int* binned0     = (int*)ws;                    ws += (long long)N_EDGES * 4;
    int* binned1     = (int*)ws;                    ws += (long long)N_EDGES * 4;
    int* adj_in      = (int*)ws;                    ws += (N_EDGES + 8) * 4;
    int* adj_out     = (int*)ws;                    ws += (N_EDGES + 8) * 4;
    int* offs_in     = (int*)ws;                    ws += (N_NODES + 1) * 4;
    int* offs_out    = (int*)ws;                    ws += (N_NODES + 1) * 4;
    int* bcnt        = (int*)ws;                    ws += 2 * N_PBKT * 4;
    int* boffs0      = (int*)ws;                    ws += (N_PBKT + 1) * 4;
    int* boffs1      = (int*)ws;                    ws += (N_PBKT + 1) * 4;
    int* gcur        = (int*)ws;                    ws += 2 * N_PBKT * 4;

    prep_w_kernel<<<(2 * 4 * 9 * 64 + 255) / 256, 256, 0, stream>>>(
        W_in, W_out, as_in, ad_in, as_out, ad_out, Wf, bcnt, adj_in, adj_out);
    hist_kernel<<<HIST_BLOCKS, 256, 0, stream>>>(ei, bcnt);

    dim3 gemm_grid((N_NODES + 127) / 128, 2);
    gemm_kernel<<<gemm_grid, 256, 0, stream>>>(
        x, Wf, h_in, h_out, asrc_in, adst_in, asrc_out, adst_out);

    bucket_scan_kernel<<<2, 512, 0, stream>>>(
        bcnt, boffs0, boffs1, gcur, offs_in, offs_out);
    partition_kernel<<<(N_EDGES + TILE_E - 1) / TILE_E, 256, 0, stream>>>(
        ei, gcur, binned0, binned1);
    place_kernel<<<dim3(N_PBKT, 2), 256, 0, stream>>>(
        binned0, binned1, boffs0, boffs1, adj_in, adj_out, offs_in, offs_out);

    gather_kernel<<<(N_NODES * 64 + 255) / 256, 256, 0, stream>>>(
        offs_in, adj_in, offs_out, adj_out, h_in, h_out,
        asrc_in, adst_in, asrc_out, adst_out, b_in, b_out, out);
}

// Round 7
// 271.936 us; speedup vs baseline: 1.7418x; 1.0326x over previous
//
#include <hip/hip_runtime.h>

#define N_NODES 100000
#define N_EDGES 800000
#define NEG 0.2f
#define PB_SHIFT 8
#define PB_NODES 256
#define N_PBKT ((N_NODES + PB_NODES - 1) / PB_NODES)   // 391
#define CAP 4096        // fixed slab capacity per bucket (mean 2048, 16-sigma headroom)
#define TILE_E 4096
#define EPT 16          // edges per thread in partition (TILE_E / 256)

typedef __attribute__((ext_vector_type(8))) short bf16x8;
typedef __attribute__((ext_vector_type(4))) float f32x4;

__device__ inline unsigned short f2bf(float f) {   // RNE f32 -> bf16
    unsigned u = __float_as_uint(f);
    u += 0x7fffu + ((u >> 16) & 1u);
    return (unsigned short)(u >> 16);
}
__device__ inline float bf2f_lo(unsigned u) { return __uint_as_float(u << 16); }
__device__ inline float bf2f_hi(unsigned u) { return __uint_as_float(u & 0xffff0000u); }

// ---------------------------------------------------------------------------
// prep_w: pack W (and Aalpha = W·a, ct==8) into MFMA B-fragment order.
// Also zeroes the slab-cursor array (doubles as bucket counts) and adj pads.
// ---------------------------------------------------------------------------
__global__ __launch_bounds__(256) void prep_w_kernel(
    const float* __restrict__ W_in, const float* __restrict__ W_out,
    const float* __restrict__ as_in, const float* __restrict__ ad_in,
    const float* __restrict__ as_out, const float* __restrict__ ad_out,
    unsigned short* __restrict__ Wf, int* __restrict__ gcur,
    int* __restrict__ adj_in, int* __restrict__ adj_out)
{
    const int t = blockIdx.x * 256 + threadIdx.x;
    if (t < 2 * N_PBKT) gcur[t] = 0;
    if (t < 8) { adj_in[N_EDGES + t] = 0; adj_out[N_EDGES + t] = 0; }
    if (t >= 2 * 4 * 9 * 64) return;
    const int lane = t & 63;
    const int rest = t >> 6;
    const int ct  = rest % 9;
    const int kb  = (rest / 9) & 3;
    const int dir = rest / 36;
    const float* W  = dir ? W_out  : W_in;
    const float* as = dir ? as_out : as_in;
    const float* ad = dir ? ad_out : ad_in;
    const int m16 = lane & 15, quad = lane >> 4;

    bf16x8 o;
#pragma unroll
    for (int j = 0; j < 8; ++j) {
        const int k = kb * 32 + quad * 8 + j;
        float v;
        if (ct < 8) {
            v = W[k * 128 + ct * 16 + m16];
        } else {
            const float* av = (m16 < 8) ? as : ad;
            const int hh = m16 & 7;
            v = 0.f;
            for (int c = 0; c < 16; ++c)
                v += W[k * 128 + hh * 16 + c] * av[hh * 16 + c];
        }
        o[j] = (short)f2bf(v);
    }
    *(bf16x8*)&Wf[(long long)t * 8] = o;
}

// ---------------------------------------------------------------------------
// gemm: h = bf16(x) @ bf16(W) via MFMA; alpha logits from the 9th column
// tile. Reads x as f32 directly, converts in-register (identical RNE).
// ---------------------------------------------------------------------------
__global__ __launch_bounds__(256) void gemm_kernel(
    const float* __restrict__ x,
    const unsigned short* __restrict__ Wf,
    unsigned short* __restrict__ h_in, unsigned short* __restrict__ h_out,
    float* __restrict__ asrc_in, float* __restrict__ adst_in,
    float* __restrict__ asrc_out, float* __restrict__ adst_out)
{
    const int dir = blockIdx.y;
    unsigned short* h = dir ? h_out : h_in;
    float* asrc = dir ? asrc_out : asrc_in;
    float* adst = dir ? adst_out : adst_in;

    const int tid  = threadIdx.x;
    const int lane = tid & 63;
    const int wave = tid >> 6;
    const int m16  = lane & 15;
    const int quad = lane >> 4;
    const int rbase = blockIdx.x * 128 + wave * 32;

    f32x4 acc[2][8];
    f32x4 acc_a[2];
#pragma unroll
    for (int rt = 0; rt < 2; ++rt) {
        acc_a[rt] = f32x4{0.f, 0.f, 0.f, 0.f};
#pragma unroll
        for (int ct = 0; ct < 8; ++ct)
            acc[rt][ct] = f32x4{0.f, 0.f, 0.f, 0.f};
    }

    const unsigned short* wf = Wf + (long long)dir * 4 * 9 * 64 * 8;

#pragma unroll
    for (int kb = 0; kb < 4; ++kb) {
        const int k0 = kb * 32 + quad * 8;
        bf16x8 a[2];
#pragma unroll
        for (int rt = 0; rt < 2; ++rt) {
            int r = rbase + rt * 16 + m16;
            r = r < N_NODES ? r : N_NODES - 1;   // clamp: stores are guarded
            const float4 v0 = *(const float4*)&x[(long long)r * 128 + k0];
            const float4 v1 = *(const float4*)&x[(long long)r * 128 + k0 + 4];
            a[rt][0] = (short)f2bf(v0.x); a[rt][1] = (short)f2bf(v0.y);
            a[rt][2] = (short)f2bf(v0.z); a[rt][3] = (short)f2bf(v0.w);
            a[rt][4] = (short)f2bf(v1.x); a[rt][5] = (short)f2bf(v1.y);
            a[rt][6] = (short)f2bf(v1.z); a[rt][7] = (short)f2bf(v1.w);
        }
#pragma unroll
        for (int ct = 0; ct < 9; ++ct) {
            const bf16x8 b = *(const bf16x8*)&wf[(long long)((kb * 9 + ct) * 64 + lane) * 8];
            if (ct < 8) {
                acc[0][ct] = __builtin_amdgcn_mfma_f32_16x16x32_bf16(a[0], b, acc[0][ct], 0, 0, 0);
                acc[1][ct] = __builtin_amdgcn_mfma_f32_16x16x32_bf16(a[1], b, acc[1][ct], 0, 0, 0);
            } else {
                acc_a[0] = __builtin_amdgcn_mfma_f32_16x16x32_bf16(a[0], b, acc_a[0], 0, 0, 0);
                acc_a[1] = __builtin_amdgcn_mfma_f32_16x16x32_bf16(a[1], b, acc_a[1], 0, 0, 0);
            }
        }
    }

#pragma unroll
    for (int rt = 0; rt < 2; ++rt) {
#pragma unroll
        for (int r = 0; r < 4; ++r) {
            const int row = rbase + rt * 16 + quad * 4 + r;
            if (row < N_NODES) {
                unsigned short* hp = &h[(long long)row * 128 + m16];
#pragma unroll
                for (int ct = 0; ct < 8; ++ct)
                    hp[ct * 16] = f2bf(acc[rt][ct][r]);
                const float av = acc_a[rt][r];
                if (m16 < 8) asrc[row * 8 + m16] = av;
                else         adst[row * 8 + (m16 - 8)] = av;
            }
        }
    }
}

// ---------------------------------------------------------------------------
// partition (fixed-slab): both direction histograms + scatters from ONE read
// of ei. LDS hist -> one global atomic per (block,bucket) reserving a run in
// bucket slab b*CAP; LDS cursors scatter within the run. gcur ends up holding
// the exact per-bucket counts (consumed by bucket_scan AFTER this kernel) —
// the separate pre-histogram pass over ei is eliminated.
// ---------------------------------------------------------------------------
__global__ __launch_bounds__(256) void partition_kernel(
    const int* __restrict__ ei, int* __restrict__ gcur,
    int* __restrict__ binned0, int* __restrict__ binned1)
{
    __shared__ int hist0[N_PBKT];
    __shared__ int curs0[N_PBKT];
    __shared__ int hist1[N_PBKT];
    __shared__ int curs1[N_PBKT];
    const int tid = threadIdx.x;
    for (int i = tid; i < N_PBKT; i += 256) { hist0[i] = 0; hist1[i] = 0; }
    __syncthreads();

    const int e0 = blockIdx.x * TILE_E;
    int sv[EPT], tv[EPT];
#pragma unroll
    for (int i = 0; i < EPT; ++i) {
        const int e = e0 + i * 256 + tid;
        if (e < N_EDGES) {
            sv[i] = ei[e];
            tv[i] = ei[N_EDGES + e];
            atomicAdd(&hist0[tv[i] >> PB_SHIFT], 1);   // dir0: group by dst
            atomicAdd(&hist1[sv[i] >> PB_SHIFT], 1);   // dir1: group by src
        } else {
            sv[i] = -1; tv[i] = 0;
        }
    }
    __syncthreads();
    for (int b = tid; b < N_PBKT; b += 256) {
        int c = hist0[b];
        curs0[b] = c ? atomicAdd(&gcur[b], c) : 0;
        c = hist1[b];
        curs1[b] = c ? atomicAdd(&gcur[N_PBKT + b], c) : 0;
    }
    __syncthreads();
#pragma unroll
    for (int i = 0; i < EPT; ++i) {
        if (sv[i] >= 0) {
            const int b0 = tv[i] >> PB_SHIFT;
            int pos = atomicAdd(&curs0[b0], 1);
            if (pos < CAP)
                binned0[b0 * CAP + pos] = (sv[i] << 8) | (tv[i] & (PB_NODES - 1));
            const int b1 = sv[i] >> PB_SHIFT;
            pos = atomicAdd(&curs1[b1], 1);
            if (pos < CAP)
                binned1[b1 * CAP + pos] = (tv[i] << 8) | (sv[i] & (PB_NODES - 1));
        }
    }
}

// ---------------------------------------------------------------------------
// bucket scan (runs AFTER partition): exclusive scan of per-bucket counts
// (gcur) -> boffs; also seeds offs[N].
// ---------------------------------------------------------------------------
__global__ __launch_bounds__(512) void bucket_scan_kernel(
    const int* __restrict__ gcur,
    int* __restrict__ boffs0, int* __restrict__ boffs1,
    int* __restrict__ offs_in, int* __restrict__ offs_out)
{
    const int dir = blockIdx.x;
    const int* c = gcur + dir * N_PBKT;
    int* bo = dir ? boffs1 : boffs0;

    __shared__ int sm[512];
    const int tid = threadIdx.x;
    const int v = (tid < N_PBKT) ? min(c[tid], CAP) : 0;
    sm[tid] = v;
    __syncthreads();
#pragma unroll
    for (int off = 1; off < 512; off <<= 1) {
        int t = (tid >= off) ? sm[tid - off] : 0;
        __syncthreads();
        sm[tid] += t;
        __syncthreads();
    }
    if (tid < N_PBKT) bo[tid] = sm[tid] - v;
    if (tid == 0) (dir ? offs_out : offs_in)[N_NODES] = N_EDGES;
}

// ---------------------------------------------------------------------------
// place: one block per bucket; reads the bucket's slab; fine count+scan+
// cursors in LDS; adj writes land in a contiguous ~8KB region.
// ---------------------------------------------------------------------------
__global__ __launch_bounds__(256) void place_kernel(
    const int* __restrict__ binned0, const int* __restrict__ binned1,
    const int* __restrict__ boffs0, const int* __restrict__ boffs1,
    const int* __restrict__ gcur,
    int* __restrict__ adj_in, int* __restrict__ adj_out,
    int* __restrict__ offs_in, int* __restrict__ offs_out)
{
    const int b   = blockIdx.x;
    const int dir = blockIdx.y;
    const int* bp = (dir ? binned1 : binned0) + b * CAP;
    const int beg = (dir ? boffs1 : boffs0)[b];
    const int cntb = min(gcur[dir * N_PBKT + b], CAP);
    int* adj  = dir ? adj_out  : adj_in;
    int* offs = dir ? offs_out : offs_in;

    const int base = b << PB_SHIFT;
    const int tid = threadIdx.x;

    __shared__ int cnt[PB_NODES];
    __shared__ int sc[PB_NODES];
    __shared__ int cur[PB_NODES];

    cnt[tid] = 0;
    __syncthreads();
    for (int p = tid; p < cntb; p += 256)
        atomicAdd(&cnt[bp[p] & (PB_NODES - 1)], 1);
    __syncthreads();
    const int v = cnt[tid];
    sc[tid] = v;
    __syncthreads();
#pragma unroll
    for (int off = 1; off < PB_NODES; off <<= 1) {
        int t = (tid >= off) ? sc[tid - off] : 0;
        __syncthreads();
        sc[tid] += t;
        __syncthreads();
    }
    const int excl = beg + sc[tid] - v;
    cur[tid] = excl;
    const int node = base + tid;
    if (node < N_NODES) offs[node] = excl;
    __syncthreads();
    for (int p = tid; p < cntb; p += 256) {
        const int pk = bp[p];
        adj[atomicAdd(&cur[pk & (PB_NODES - 1)], 1)] = pk >> 8;
    }
}

// ---------------------------------------------------------------------------
// Gather v5 (round-3 form, the best measured): one wave per node, wave-
// uniform n so offs/adj go through the scalar pipe; single padded branch-
// free 8-stride loop; inline asrc+leaky+exp; shfl w-broadcast; den via
// 3x shfl_xor. (Round-6's LDS-broadcast variant measured +2.7us — reverted.)
// ---------------------------------------------------------------------------
__global__ __launch_bounds__(256) void gather_kernel(
    const int* __restrict__ offs_in, const int* __restrict__ adj_in,
    const int* __restrict__ offs_out, const int* __restrict__ adj_out,
    const unsigned short* __restrict__ h_in, const unsigned short* __restrict__ h_out,
    const float* __restrict__ asrc_in, const float* __restrict__ adst_in,
    const float* __restrict__ asrc_out, const float* __restrict__ adst_out,
    const float* __restrict__ b_in, const float* __restrict__ b_out,
    float* __restrict__ out)
{
    int n = (blockIdx.x * 256 + threadIdx.x) >> 6;
    if (n >= N_NODES) return;
    n = __builtin_amdgcn_readfirstlane(n);
    const int lane = threadIdx.x & 63;
    const int c0 = lane * 2;
    const int hh = lane >> 3;        // head this lane accumulates for
    const int g8 = lane & 7;         // neighbor slot this lane owns
    const int grpbase = lane & 56;   // hh*8: base lane of this head group

    float acc0 = b_in[c0] + b_out[c0];
    float acc1 = b_in[c0 + 1] + b_out[c0 + 1];

#define DIR_BLOCK(OFFS, ADJ, HX, ASRC, ADST)                                   \
    {                                                                          \
        const int beg = OFFS[n], end = OFFS[n + 1];                            \
        if (end > beg) {                                                       \
            const float ad = ADST[n * 8 + hh];                                 \
            float num0 = 0.f, num1 = 0.f, den = 0.f;                           \
            for (int p = beg; p < end; p += 8) {                               \
                const int q = p + g8;                                          \
                const int nbv = ADJ[q];               /* vector ld, padded */  \
                float l = ASRC[nbv * 8 + hh] + ad;                             \
                l = l > 0.f ? l : NEG * l;                                     \
                float w = __expf(l);                                           \
                w = (q < end) ? w : 0.f;                                       \
                den += w;                                                      \
                _Pragma("unroll")                                              \
                for (int g = 0; g < 8; ++g) {                                  \
                    const int nb = ADJ[p + g];        /* scalar (uniform) */   \
                    const float w_g = __shfl(w, grpbase + g, 64);              \
                    const unsigned hv = *(const unsigned*)&HX[(long long)nb * 128 + c0]; \
                    num0 += w_g * bf2f_lo(hv);                                 \
                    num1 += w_g * bf2f_hi(hv);                                 \
                }                                                              \
            }                                                                  \
            den += __shfl_xor(den, 1, 64);                                     \
            den += __shfl_xor(den, 2, 64);                                     \
            den += __shfl_xor(den, 4, 64);                                     \
            const float rden = 1.f / den;                                      \
            acc0 += num0 * rden;                                               \
            acc1 += num1 * rden;                                               \
        }                                                                      \
    }

    DIR_BLOCK(offs_in, adj_in, h_in, asrc_in, adst_in)
    DIR_BLOCK(offs_out, adj_out, h_out, asrc_out, adst_out)
#undef DIR_BLOCK

    *(float2*)&out[(long long)n * 128 + c0] = float2{acc0, acc1};
}

extern "C" void kernel_launch(void* const* d_in, const int* in_sizes, int n_in,
                              void* d_out, int out_size, void* d_ws, size_t ws_size,
                              hipStream_t stream) {
    const float* x      = (const float*)d_in[0];
    const int*   ei     = (const int*)  d_in[1];
    const float* W_in   = (const float*)d_in[2];
    const float* as_in  = (const float*)d_in[3];
    const float* ad_in  = (const float*)d_in[4];
    const float* b_in   = (const float*)d_in[5];
    const float* W_out  = (const float*)d_in[6];
    const float* as_out = (const float*)d_in[7];
    const float* ad_out = (const float*)d_in[8];
    const float* b_out  = (const float*)d_in[9];
    float* out = (float*)d_out;

    char* ws = (char*)d_ws;
    const long long NH = (long long)N_NODES * 128;
    unsigned short* h_in  = (unsigned short*)ws;    ws += NH * 2;
    unsigned short* h_out = (unsigned short*)ws;    ws += NH * 2;
    unsigned short* Wf    = (unsigned short*)ws;    ws += 2LL * 4 * 9 * 64 * 8 * 2;
    float* asrc_in   = (float*)ws;                  ws += N_NODES * 8 * 4;
    float* adst_in   = (float*)ws;                  ws += N_NODES * 8 * 4;
    float* asrc_out  = (float*)ws;                  ws += N_NODES * 8 * 4;
    float* adst_out  = (float*)ws;                  ws += N_NODES * 8 * 4;
    int* binned0     = (int*)ws;                    ws += (long long)N_PBKT * CAP * 4;
    int* binned1     = (int*)ws;                    ws += (long long)N_PBKT * CAP * 4;
    int* adj_in      = (int*)ws;                    ws += (N_EDGES + 8) * 4;
    int* adj_out     = (int*)ws;                    ws += (N_EDGES + 8) * 4;
    int* offs_in     = (int*)ws;                    ws += (N_NODES + 1) * 4;
    int* offs_out    = (int*)ws;                    ws += (N_NODES + 1) * 4;
    int* gcur        = (int*)ws;                    ws += 2 * N_PBKT * 4;
    int* boffs0      = (int*)ws;                    ws += (N_PBKT + 1) * 4;
    int* boffs1      = (int*)ws;                    ws += (N_PBKT + 1) * 4;

    prep_w_kernel<<<(2 * 4 * 9 * 64 + 255) / 256, 256, 0, stream>>>(
        W_in, W_out, as_in, ad_in, as_out, ad_out, Wf, gcur, adj_in, adj_out);

    dim3 gemm_grid((N_NODES + 127) / 128, 2);
    gemm_kernel<<<gemm_grid, 256, 0, stream>>>(
        x, Wf, h_in, h_out, asrc_in, adst_in, asrc_out, adst_out);

    partition_kernel<<<(N_EDGES + TILE_E - 1) / TILE_E, 256, 0, stream>>>(
        ei, gcur, binned0, binned1);
    bucket_scan_kernel<<<2, 512, 0, stream>>>(
        gcur, boffs0, boffs1, offs_in, offs_out);
    place_kernel<<<dim3(N_PBKT, 2), 256, 0, stream>>>(
        binned0, binned1, boffs0, boffs1, gcur, adj_in, adj_out, offs_in, offs_out);

    gather_kernel<<<(N_NODES * 64 + 255) / 256, 256, 0, stream>>>(
        offs_in, adj_in, offs_out, adj_out, h_in, h_out,
        asrc_in, adst_in, asrc_out, adst_out, b_in, b_out, out);
}